// Round 1
// baseline (114.228 us; speedup 1.0000x reference)
//
#include <hip/hip_runtime.h>
#include <hip/hip_bf16.h>

#define CC    32
#define HH    80
#define WW    80
#define HW    6400     // 80*80
#define HPQ   77
#define WPQ   77
#define PP    5929     // 77*77
#define DD    512      // 32*4*4
#define MSTR  81
#define NTILE 93       // 93 candidate blocks of 64
#define QTILES 372     // 5952/16 worst-case query tiles
#define NEGINF (-1e9f)

typedef __attribute__((ext_vector_type(4))) float f32x4;
typedef __attribute__((ext_vector_type(8))) short bf16x8;
typedef __attribute__((ext_vector_type(8))) unsigned short u16x8;

__device__ __forceinline__ void split_bf16(float v, unsigned short& hi, unsigned short& lo) {
    __hip_bfloat16 h = __float2bfloat16(v);
    float hf = __bfloat162float(h);
    __hip_bfloat16 lw = __float2bfloat16(v - hf);
    hi = *reinterpret_cast<unsigned short*>(&h);
    lo = *reinterpret_cast<unsigned short*>(&lw);
}

// ---------------- flags: invn, excl, qslot (-1 = invalid), compacted valid list ----------------
__global__ __launch_bounds__(256) void k_flags(const float* __restrict__ low,
                                               const int* __restrict__ mask,
                                               float* __restrict__ invn,
                                               int* __restrict__ excl,
                                               int* __restrict__ qslot,
                                               int* __restrict__ qlist,
                                               int* __restrict__ nvalid) {
    __shared__ float part[4][64];
    const int tid = threadIdx.x;
    const int pl = tid & 63;
    const int sl = tid >> 6;           // channel slice 0..3
    const int p = blockIdx.x * 64 + pl;

    float s = 0.f;
    if (p < PP) {
        int pi = p / WPQ, pj = p % WPQ;
        int base = pi * WW + pj;
        for (int c = sl * 8; c < sl * 8 + 8; ++c) {
            int b2 = c * HW + base;
#pragma unroll
            for (int di = 0; di < 4; ++di)
#pragma unroll
                for (int dj = 0; dj < 4; ++dj) {
                    float v = low[b2 + di * WW + dj];
                    s += v * v;
                }
        }
    }
    part[sl][pl] = s;
    __syncthreads();
    if (tid < 64 && p < PP) {
        float t = part[0][tid] + part[1][tid] + part[2][tid] + part[3][tid];
        invn[p] = 1.0f / (sqrtf(t) + 1e-6f);
        int pi = p / WPQ, pj = p % WPQ;
        int m00 = mask[pi * MSTR + pj];
        int m01 = mask[pi * MSTR + pj + 4];
        int m10 = mask[(pi + 4) * MSTR + pj];
        int m11 = mask[(pi + 4) * MSTR + pj + 4];
        excl[p] = (m00 == 1) ? 1 : 0;
        int v = (m00 != 0 && m01 != 0 && m10 != 0 && m11 != 0) ? 1 : 0;
        int slot = -1;
        if (v) {
            slot = atomicAdd(nvalid, 1);
            qlist[slot] = p;
        }
        qslot[p] = slot;
    }
}

// ---------------- pack A and B (fused): bf16 hi/lo in MFMA frag order ----------------
// layout: [tile u][kstep s][lane l][j 0..7]; lane: n=l&15, k=s*32+(l>>4)*8+j
__global__ __launch_bounds__(256) void k_pack(const float* __restrict__ low,
                                              const float* __restrict__ high,
                                              const float* __restrict__ invn,
                                              const int* __restrict__ qlist,
                                              const int* __restrict__ nvalid,
                                              unsigned short* __restrict__ Bhi,
                                              unsigned short* __restrict__ Blo,
                                              unsigned short* __restrict__ Ahi,
                                              unsigned short* __restrict__ Alo) {
    const int g = blockIdx.x;
    if (g < QTILES * 4) {
        // ---- B: low * invn, all 372 tiles ----
        int t = g * 256 + threadIdx.x;
        int l = t & 63;
        int s = (t >> 6) & 15;
        int u = t >> 10;
        int n = l & 15, quad = l >> 4;
        int p = u * 16 + n;
        int kbase = s * 32 + quad * 8;
        u16x8 vh, vl;
        if (p < PP) {
            float sc = invn[p];
            int pi = p / WPQ, pj = p % WPQ;
            int base = (kbase >> 4) * HW + pi * WW + pj;   // c fixed across j
#pragma unroll
            for (int j = 0; j < 8; ++j) {
                int kk = kbase + j;
                int di = (kk >> 2) & 3, dj = kk & 3;
                float v = low[base + di * WW + dj] * sc;
                unsigned short h, lo;
                split_bf16(v, h, lo);
                vh[j] = h; vl[j] = lo;
            }
        } else {
#pragma unroll
            for (int j = 0; j < 8; ++j) { vh[j] = 0; vl[j] = 0; }
        }
        int off = t * 8;
        *reinterpret_cast<u16x8*>(Bhi + off) = vh;
        *reinterpret_cast<u16x8*>(Blo + off) = vl;
    } else {
        // ---- A: high (compacted valid queries), only active tiles ----
        int t = (g - QTILES * 4) * 256 + threadIdx.x;
        int nv = *nvalid;
        int l = t & 63;
        int s = (t >> 6) & 15;
        int u = t >> 10;
        if ((u >> 2) * 64 >= nv) return;              // qblk inactive -> frags never read
        int m = l & 15, quad = l >> 4;
        int slot = u * 16 + m;
        int kbase = s * 32 + quad * 8;
        u16x8 vh, vl;
        if (slot < nv) {
            int q = qlist[slot];
            int qi = q / WPQ, qj = q % WPQ;
            int base = (kbase >> 4) * HW + qi * WW + qj;
#pragma unroll
            for (int j = 0; j < 8; ++j) {
                int kk = kbase + j;
                int di = (kk >> 2) & 3, dj = kk & 3;
                float v = high[base + di * WW + dj];
                unsigned short h, lo;
                split_bf16(v, h, lo);
                vh[j] = h; vl[j] = lo;
            }
        } else {
#pragma unroll
            for (int j = 0; j < 8; ++j) { vh[j] = 0; vl[j] = 0; }
        }
        int off = t * 8;
        *reinterpret_cast<u16x8*>(Ahi + off) = vh;
        *reinterpret_cast<u16x8*>(Alo + off) = vl;
    }
}

// ---------------- score: 64q x 64c per wave, bf16-split MFMA + packed atomic argmax ----------------
// grid (24, 12), 256 thr = 4 waves; wave w handles pblk = bx*4+w (4 ptiles) x qblk (4 qtiles).
// qblk strided by 12 so any nv up to 5929 is covered; typical nv~371 -> 1 iteration.
__global__ __launch_bounds__(256) void k_score(const unsigned short* __restrict__ Ahi,
                                               const unsigned short* __restrict__ Alo,
                                               const unsigned short* __restrict__ Bhi,
                                               const unsigned short* __restrict__ Blo,
                                               const int* __restrict__ excl,
                                               const int* __restrict__ nvalid,
                                               unsigned long long* __restrict__ bestpk) {
    const int nv = *nvalid;
    const int w = threadIdx.x >> 6;
    const int l = threadIdx.x & 63;
    const int pblk = blockIdx.x * 4 + w;          // 0..95 (93..95: B pad tiles, guarded below)
    const int n = l & 15, quad = l >> 4;
    const int bbase = pblk * 4 * 8192 + l * 8;

    // hoist per-pt candidate index / exclusion (pblk-fixed)
    int gpv[4]; bool exv[4];
#pragma unroll
    for (int pt = 0; pt < 4; ++pt) {
        gpv[pt] = pblk * 64 + pt * 16 + n;
        exv[pt] = (gpv[pt] < PP) ? (excl[gpv[pt]] != 0) : true;
    }

    for (int qblk = blockIdx.y; qblk * 64 < nv; qblk += 12) {
        f32x4 acc[4][4];
#pragma unroll
        for (int qt = 0; qt < 4; ++qt)
#pragma unroll
            for (int pt = 0; pt < 4; ++pt) acc[qt][pt] = (f32x4){0.f, 0.f, 0.f, 0.f};

        const int abase = qblk * 4 * 8192 + l * 8;
#pragma unroll 2
        for (int s = 0; s < 16; ++s) {
            bf16x8 ah[4], al[4];
#pragma unroll
            for (int qt = 0; qt < 4; ++qt) {
                ah[qt] = *reinterpret_cast<const bf16x8*>(Ahi + abase + qt * 8192 + s * 512);
                al[qt] = *reinterpret_cast<const bf16x8*>(Alo + abase + qt * 8192 + s * 512);
            }
#pragma unroll
            for (int pt = 0; pt < 4; ++pt) {
                bf16x8 bh = *reinterpret_cast<const bf16x8*>(Bhi + bbase + pt * 8192 + s * 512);
                bf16x8 bl = *reinterpret_cast<const bf16x8*>(Blo + bbase + pt * 8192 + s * 512);
#pragma unroll
                for (int qt = 0; qt < 4; ++qt) {
                    acc[qt][pt] = __builtin_amdgcn_mfma_f32_16x16x32_bf16(ah[qt], bh, acc[qt][pt], 0, 0, 0);
                    acc[qt][pt] = __builtin_amdgcn_mfma_f32_16x16x32_bf16(ah[qt], bl, acc[qt][pt], 0, 0, 0);
                    acc[qt][pt] = __builtin_amdgcn_mfma_f32_16x16x32_bf16(al[qt], bh, acc[qt][pt], 0, 0, 0);
                }
            }
        }

        // C/D: col n = l&15 (candidate), row m = quad*4 + r (query within qtile)
#pragma unroll
        for (int qt = 0; qt < 4; ++qt) {
            float bs[4]; int bi[4];
#pragma unroll
            for (int r = 0; r < 4; ++r) { bs[r] = -3.4e38f; bi[r] = 0x7fffffff; }
#pragma unroll
            for (int pt = 0; pt < 4; ++pt) {
                if (gpv[pt] < PP) {
#pragma unroll
                    for (int r = 0; r < 4; ++r) {
                        float sv = exv[pt] ? NEGINF : acc[qt][pt][r];
                        if (sv > bs[r]) { bs[r] = sv; bi[r] = gpv[pt]; }  // pt asc -> lowest gp on tie
                    }
                }
            }
            // reduce over the 16 lanes of this quad-row group
#pragma unroll
            for (int off = 1; off <= 8; off <<= 1) {
#pragma unroll
                for (int r = 0; r < 4; ++r) {
                    float s2 = __shfl_xor(bs[r], off, 64);
                    int   i2 = __shfl_xor(bi[r], off, 64);
                    if (s2 > bs[r] || (s2 == bs[r] && i2 < bi[r])) { bs[r] = s2; bi[r] = i2; }
                }
            }
            if (n == 0) {
#pragma unroll
                for (int r = 0; r < 4; ++r) {
                    if (bi[r] != 0x7fffffff) {
                        // monotone float->uint map; pack with ~idx so ties pick lowest idx
                        unsigned ub = __float_as_uint(bs[r]);
                        unsigned mo = (ub & 0x80000000u) ? ~ub : (ub | 0x80000000u);
                        unsigned long long pk =
                            ((unsigned long long)mo << 32) | (unsigned)(~bi[r]);
                        int slot = (qblk * 4 + qt) * 16 + quad * 4 + r;
                        atomicMax(bestpk + slot, pk);
                    }
                }
            }
        }
    }
}

// ---------------- fused prep + gather + overlap-add + normalize ----------------
// block = 64 pixels: phase1 builds per-pixel offlist in LDS, phase2 does 32 channels.
__global__ __launch_bounds__(256) void k_out(const float* __restrict__ low,
                                             const int* __restrict__ qslot,
                                             const unsigned long long* __restrict__ bestpk,
                                             float* __restrict__ out) {
    __shared__ int scnt[64];
    __shared__ int soff[64][17];   // +1 pad: stride 17 breaks bank conflicts
    const int tid = threadIdx.x;
    const int pixb = blockIdx.x * 64;
    if (tid < 64) {
        int pix = pixb + tid;
        int i = pix / WW, j = pix % WW;
        int nn = 0;
#pragma unroll
        for (int di = 0; di < 4; ++di) {
            int qi = i - di;
            if (qi < 0 || qi >= HPQ) continue;
#pragma unroll
            for (int dj = 0; dj < 4; ++dj) {
                int qj = j - dj;
                if (qj < 0 || qj >= WPQ) continue;
                int sl = qslot[qi * WPQ + qj];
                if (sl >= 0) {
                    int b = (int)(~(unsigned)bestpk[sl]);   // low 32 bits = ~best_idx
                    soff[tid][nn++] = (b / WPQ + di) * WW + (b % WPQ + dj);
                }
            }
        }
        scnt[tid] = nn;
    }
    __syncthreads();
    const int pl = tid & 63, cg = tid >> 6;
    const int nn = scnt[pl];
    const int pix = pixb + pl;
    const float inv = 1.0f / ((float)nn + 1e-6f);
#pragma unroll
    for (int k = 0; k < 8; ++k) {
        int c = cg * 8 + k;
        int base = c * HW;
        float a;
        if (nn > 0) {
            a = 0.f;
            for (int t2 = 0; t2 < nn; ++t2) a += low[base + soff[pl][t2]];
            a *= inv;
        } else {
            a = low[base + pix];
        }
        out[base + pix] = a;
    }
}

extern "C" void kernel_launch(void* const* d_in, const int* in_sizes, int n_in,
                              void* d_out, int out_size, void* d_ws, size_t ws_size,
                              hipStream_t stream) {
    const float* low  = (const float*)d_in[0];
    const float* high = (const float*)d_in[1];
    const int*   mask = (const int*)d_in[2];
    float* out = (float*)d_out;

    char* ws = (char*)d_ws;
    int* nvalid = (int*)ws;                                       // 64 B
    unsigned long long* bestpk = (unsigned long long*)(ws + 64);  // 6144*8 = 49152 -> 49216
    int*   qlist = (int*)(ws + 49216);                            // 23808 -> 73024
    int*   qslot = (int*)(ws + 73024);                            // 23808 -> 96832
    float* invn  = (float*)(ws + 96832);                          // 23808 -> 120640
    int*   excl  = (int*)(ws + 120640);                           // 23808 -> 144448
    unsigned short* Ahi = (unsigned short*)(ws + 144448);         // 372 tiles: 6,094,848
    unsigned short* Alo = (unsigned short*)(ws + 6239296);        // 6,094,848
    unsigned short* Bhi = (unsigned short*)(ws + 12334144);       // 384 tiles: 6,291,456 (pad tiles
    unsigned short* Blo = (unsigned short*)(ws + 18625600);       //  readable-garbage, gp>=PP guarded)
                                                                  // end 24,917,056 (~24.9 MB)

    hipMemsetAsync(ws, 0, 49216, stream);   // nvalid + bestpk
    hipLaunchKernelGGL(k_flags, dim3(NTILE), dim3(256), 0, stream,
                       low, mask, invn, excl, qslot, qlist, nvalid);
    hipLaunchKernelGGL(k_pack, dim3(QTILES * 8), dim3(256), 0, stream,
                       low, high, invn, qlist, nvalid, Bhi, Blo, Ahi, Alo);
    hipLaunchKernelGGL(k_score, dim3(24, 12), dim3(256), 0, stream,
                       Ahi, Alo, Bhi, Blo, excl, nvalid, bestpk);
    hipLaunchKernelGGL(k_out, dim3(100), dim3(256), 0, stream,
                       low, qslot, bestpk, out);
}